// Round 2
// baseline (2066.358 us; speedup 1.0000x reference)
//
#include <hip/hip_runtime.h>
#include <hip/hip_bf16.h>

// Problem constants
#define Hn 16
#define Mn 1024
#define Kn 64
#define Vn 64
#define FFn 4096
#define Bn 2
#define Cn 2048
#define EPSf 1e-5f

// ---------------------------------------------------------------------------
// Generic tiled fp32 GEMM:  C[row,n] = sum_k A[row,k]*B[k,n] (+bias) (opt relu)
// BM=128, BN=64, BK=16, 256 threads, 8x4 micro-tile per thread.
// grid = (N/64, Mrows/128, batch)
// Batch addressing: A += (z/aDiv)*aStride; B += (z%bMod)*bStride; C += z*cStride
// ---------------------------------------------------------------------------
template <bool RELU, bool BIAS>
__global__ __launch_bounds__(256) void gemm_t(
    const float* __restrict__ A, const float* __restrict__ Bm,
    const float* __restrict__ bias, float* __restrict__ Cc,
    int Kdim, int lda, int ldb, int ldc,
    int aDiv, long aStride, int bMod, long bStride, long cStride)
{
    __shared__ float sA[16][132];   // [k][m], padded: rows 528B (16B-aligned), 2-way max
    __shared__ float sB[16][68];    // [k][n], padded: rows 272B (16B-aligned)

    const int z = blockIdx.z;
    const float* Ab = A + (long)(z / aDiv) * aStride;
    const float* Bb = Bm + (long)(z % bMod) * bStride;
    float* Cb = Cc + (long)z * cStride;

    const int row0 = blockIdx.y * 128;
    const int n0   = blockIdx.x * 64;
    const int t  = threadIdx.x;
    const int tx = t & 15, ty = t >> 4;
    const int ar = ty * 8, bc = tx * 4;
    const int lr = t >> 1, lk = (t & 1) * 8;   // A tile loads: 128 rows x 16 k
    const int br = t >> 4, bn = (t & 15) * 4;  // B tile loads: 16 k x 64 n

    float acc[8][4];
#pragma unroll
    for (int i = 0; i < 8; ++i)
#pragma unroll
        for (int j = 0; j < 4; ++j) acc[i][j] = 0.f;

    for (int k0 = 0; k0 < Kdim; k0 += 16) {
        float4 a0 = *(const float4*)&Ab[(long)(row0 + lr) * lda + k0 + lk];
        float4 a1 = *(const float4*)&Ab[(long)(row0 + lr) * lda + k0 + lk + 4];
        float4 bv = *(const float4*)&Bb[(long)(k0 + br) * ldb + n0 + bn];
        __syncthreads();  // previous tile fully consumed before overwrite
        sA[lk + 0][lr] = a0.x; sA[lk + 1][lr] = a0.y;
        sA[lk + 2][lr] = a0.z; sA[lk + 3][lr] = a0.w;
        sA[lk + 4][lr] = a1.x; sA[lk + 5][lr] = a1.y;
        sA[lk + 6][lr] = a1.z; sA[lk + 7][lr] = a1.w;
        *(float4*)&sB[br][bn] = bv;
        __syncthreads();
#pragma unroll
        for (int kk = 0; kk < 16; ++kk) {
            float4 A0 = *(const float4*)&sA[kk][ar];
            float4 A1 = *(const float4*)&sA[kk][ar + 4];
            float4 Bv = *(const float4*)&sB[kk][bc];
            float aa[8] = {A0.x, A0.y, A0.z, A0.w, A1.x, A1.y, A1.z, A1.w};
            float bb[4] = {Bv.x, Bv.y, Bv.z, Bv.w};
#pragma unroll
            for (int i = 0; i < 8; ++i)
#pragma unroll
                for (int j = 0; j < 4; ++j)
                    acc[i][j] += aa[i] * bb[j];
        }
    }

    float4 bv4 = make_float4(0.f, 0.f, 0.f, 0.f);
    if (BIAS) bv4 = *(const float4*)&bias[n0 + bc];
#pragma unroll
    for (int i = 0; i < 8; ++i) {
        float4 r;
        r.x = acc[i][0] + (BIAS ? bv4.x : 0.f);
        r.y = acc[i][1] + (BIAS ? bv4.y : 0.f);
        r.z = acc[i][2] + (BIAS ? bv4.z : 0.f);
        r.w = acc[i][3] + (BIAS ? bv4.w : 0.f);
        if (RELU) {
            r.x = fmaxf(r.x, 0.f); r.y = fmaxf(r.y, 0.f);
            r.z = fmaxf(r.z, 0.f); r.w = fmaxf(r.w, 0.f);
        }
        *(float4*)&Cb[(long)(row0 + ar + i) * ldc + n0 + bc] = r;
    }
}

// ---------------------------------------------------------------------------
// Flash attention (fp32). One block = one (b,h) x 64 queries. Key tiles of 32.
// q,k,v layout: (B*H, C, 64). Output pre2 layout: (b, d, h, v) = (B*C, H*V)
// so the wo projection is a plain row-major GEMM.
// Scores s[c][q] -> online softmax over c (keys) -> O += P^T V.
// qT pre-scaled by 1/sqrt(K)=0.125.
// ---------------------------------------------------------------------------
__global__ __launch_bounds__(256) void attn_flash(
    const float* __restrict__ qg, const float* __restrict__ kg,
    const float* __restrict__ vg, float* __restrict__ pre2)
{
    __shared__ float qT[64][64];   // [d][q]
    __shared__ float kT[64][34];   // [d][c]   (pad: float2 rows stay 8B aligned)
    __shared__ float vsh[32][68];  // [c][v]
    __shared__ float ps[64][34];   // [q][c]   scores then probabilities
    __shared__ float m_s[64], l_s[64], sc_s[64];
    __shared__ float red[4][64];

    const int bh = blockIdx.y;           // b*H + h
    const int b = bh >> 4, h = bh & 15;
    const int q0 = blockIdx.x * 64;
    const int t = threadIdx.x;
    const long base = (long)bh * (Cn * 64);

    // load q tile transposed, scaled by 0.125 (4 float4 per thread)
    {
        const int qi = t >> 2;
        const int dq = (t & 3) * 16;
#pragma unroll
        for (int u = 0; u < 4; ++u) {
            float4 v4 = *(const float4*)&qg[base + (long)(q0 + qi) * 64 + dq + u * 4];
            qT[dq + u * 4 + 0][qi] = v4.x * 0.125f;
            qT[dq + u * 4 + 1][qi] = v4.y * 0.125f;
            qT[dq + u * 4 + 2][qi] = v4.z * 0.125f;
            qT[dq + u * 4 + 3][qi] = v4.w * 0.125f;
        }
    }
    if (t < 64) { m_s[t] = -1e30f; l_s[t] = 0.f; }

    float o[4][4];
#pragma unroll
    for (int i = 0; i < 4; ++i)
#pragma unroll
        for (int j = 0; j < 4; ++j) o[i][j] = 0.f;

    const int sqr = (t & 15) * 4;   // score micro: 4 q
    const int scr = (t >> 4) * 2;   // score micro: 2 c
    const int pqr = (t >> 4) * 4;   // pv micro: 4 q
    const int pvr = (t & 15) * 4;   // pv micro: 4 v
    const int qq = t & 63, part = t >> 6;

    for (int c0 = 0; c0 < Cn; c0 += 32) {
        __syncthreads();  // (A) prev PV done before k/v overwrite
        {
            const int ci = t >> 3;
            const int dq = (t & 7) * 8;
#pragma unroll
            for (int u = 0; u < 2; ++u) {
                float4 k4 = *(const float4*)&kg[base + (long)(c0 + ci) * 64 + dq + u * 4];
                kT[dq + u * 4 + 0][ci] = k4.x;
                kT[dq + u * 4 + 1][ci] = k4.y;
                kT[dq + u * 4 + 2][ci] = k4.z;
                kT[dq + u * 4 + 3][ci] = k4.w;
                float4 v4 = *(const float4*)&vg[base + (long)(c0 + ci) * 64 + dq + u * 4];
                *(float4*)&vsh[ci][dq + u * 4] = v4;
            }
        }
        __syncthreads();  // (B) tiles loaded

        // scores: 4q x 2c per thread over d=0..63
        {
            float sc00 = 0.f, sc01 = 0.f, sc10 = 0.f, sc11 = 0.f;
            float sc20 = 0.f, sc21 = 0.f, sc30 = 0.f, sc31 = 0.f;
#pragma unroll 16
            for (int d = 0; d < 64; ++d) {
                float4 q4 = *(const float4*)&qT[d][sqr];
                float2 k2 = *(const float2*)&kT[d][scr];
                sc00 += q4.x * k2.x; sc01 += q4.x * k2.y;
                sc10 += q4.y * k2.x; sc11 += q4.y * k2.y;
                sc20 += q4.z * k2.x; sc21 += q4.z * k2.y;
                sc30 += q4.w * k2.x; sc31 += q4.w * k2.y;
            }
            ps[sqr + 0][scr] = sc00; ps[sqr + 0][scr + 1] = sc01;
            ps[sqr + 1][scr] = sc10; ps[sqr + 1][scr + 1] = sc11;
            ps[sqr + 2][scr] = sc20; ps[sqr + 2][scr + 1] = sc21;
            ps[sqr + 3][scr] = sc30; ps[sqr + 3][scr + 1] = sc31;
        }
        __syncthreads();  // (C)

        // online softmax over this tile's 32 keys
        {
            float mx = -1e30f;
#pragma unroll
            for (int i = 0; i < 8; ++i) mx = fmaxf(mx, ps[qq][part * 8 + i]);
            red[part][qq] = mx;
        }
        __syncthreads();  // (D)
        if (t < 64) {
            float tm = fmaxf(fmaxf(red[0][t], red[1][t]), fmaxf(red[2][t], red[3][t]));
            float mo = m_s[t];
            float mn = fmaxf(mo, tm);
            float f = __expf(mo - mn);
            m_s[t] = mn; sc_s[t] = f; l_s[t] *= f;
        }
        __syncthreads();  // (E)
        {
            float mn = m_s[qq];
            float sum = 0.f;
#pragma unroll
            for (int i = 0; i < 8; ++i) {
                float e = __expf(ps[qq][part * 8 + i] - mn);
                ps[qq][part * 8 + i] = e;
                sum += e;
            }
            red[part][qq] = sum;
        }
        __syncthreads();  // (F)
        if (t < 64) l_s[t] += red[0][t] + red[1][t] + red[2][t] + red[3][t];

        // PV accumulate: rescale O then O[q][v] += sum_c P[q][c] * V[c][v]
        {
            float f0 = sc_s[pqr + 0], f1 = sc_s[pqr + 1];
            float f2 = sc_s[pqr + 2], f3 = sc_s[pqr + 3];
#pragma unroll
            for (int j = 0; j < 4; ++j) {
                o[0][j] *= f0; o[1][j] *= f1; o[2][j] *= f2; o[3][j] *= f3;
            }
#pragma unroll 8
            for (int c = 0; c < 32; ++c) {
                float p0 = ps[pqr + 0][c], p1 = ps[pqr + 1][c];
                float p2 = ps[pqr + 2][c], p3 = ps[pqr + 3][c];
                float4 v4 = *(const float4*)&vsh[c][pvr];
                o[0][0] += p0 * v4.x; o[0][1] += p0 * v4.y; o[0][2] += p0 * v4.z; o[0][3] += p0 * v4.w;
                o[1][0] += p1 * v4.x; o[1][1] += p1 * v4.y; o[1][2] += p1 * v4.z; o[1][3] += p1 * v4.w;
                o[2][0] += p2 * v4.x; o[2][1] += p2 * v4.y; o[2][2] += p2 * v4.z; o[2][3] += p2 * v4.w;
                o[3][0] += p3 * v4.x; o[3][1] += p3 * v4.y; o[3][2] += p3 * v4.z; o[3][3] += p3 * v4.w;
            }
        }
    }
    __syncthreads();  // l_s final

#pragma unroll
    for (int i = 0; i < 4; ++i) {
        float inv = 1.0f / l_s[pqr + i];
        float4 r;
        r.x = o[i][0] * inv; r.y = o[i][1] * inv;
        r.z = o[i][2] * inv; r.w = o[i][3] * inv;
        // pre2 layout: ((b*C + d)*H + h)*V + v
        *(float4*)&pre2[(((long)b * Cn + q0 + pqr + i) * Hn + h) * Vn + pvr] = r;
    }
}

// ---------------------------------------------------------------------------
// Fused residual + LayerNorm: out[row,:] = LN(a[row,:] + r[row,:]) * g + b
// One block per row (M=1024), 256 threads x 4 elements.
// ---------------------------------------------------------------------------
__global__ __launch_bounds__(256) void ln_res(
    const float* __restrict__ a, const float* __restrict__ r,
    const float* __restrict__ g, const float* __restrict__ be,
    float* __restrict__ out)
{
    __shared__ float wsum[4];
    __shared__ float wsum2[4];
    const long row = blockIdx.x;
    const int t = threadIdx.x;
    float4 va = *(const float4*)&a[row * Mn + t * 4];
    float4 vb = *(const float4*)&r[row * Mn + t * 4];
    float v0 = va.x + vb.x, v1 = va.y + vb.y, v2 = va.z + vb.z, v3 = va.w + vb.w;

    float s = v0 + v1 + v2 + v3;
#pragma unroll
    for (int off = 32; off > 0; off >>= 1) s += __shfl_xor(s, off, 64);
    if ((t & 63) == 0) wsum[t >> 6] = s;
    __syncthreads();
    float mu = (wsum[0] + wsum[1] + wsum[2] + wsum[3]) * (1.0f / Mn);

    float d0 = v0 - mu, d1 = v1 - mu, d2 = v2 - mu, d3 = v3 - mu;
    float s2 = d0 * d0 + d1 * d1 + d2 * d2 + d3 * d3;
#pragma unroll
    for (int off = 32; off > 0; off >>= 1) s2 += __shfl_xor(s2, off, 64);
    if ((t & 63) == 0) wsum2[t >> 6] = s2;
    __syncthreads();
    float var = (wsum2[0] + wsum2[1] + wsum2[2] + wsum2[3]) * (1.0f / Mn);
    float rstd = rsqrtf(var + EPSf);

    float4 g4 = *(const float4*)&g[t * 4];
    float4 b4 = *(const float4*)&be[t * 4];
    float4 r4;
    r4.x = d0 * rstd * g4.x + b4.x;
    r4.y = d1 * rstd * g4.y + b4.y;
    r4.z = d2 * rstd * g4.z + b4.z;
    r4.w = d3 * rstd * g4.w + b4.w;
    *(float4*)&out[row * Mn + t * 4] = r4;
}

// ---------------------------------------------------------------------------
// Orchestration.
// Workspace layout (floats), peak 24M floats = 96 MB:
//   qb    : [0,  4M)   (B*H,C,64)
//   kb    : [4M, 8M)
//   vb    : [8M, 12M)
//   pre2  : [12M,16M)  (B*C, H*V)
//   attn_tmp = [0,4M)   reuses qb   (K3 reads pre2, writes here)
//   h1       = [4M,8M)  reuses kb
//   sbuf     = [8M,24M) reuses vb+pre2 (FFN hidden, 4096x4096)
//   ffn_tmp  = [0,4M)   reuses attn_tmp
// ---------------------------------------------------------------------------
extern "C" void kernel_launch(void* const* d_in, const int* in_sizes, int n_in,
                              void* d_out, int out_size, void* d_ws, size_t ws_size,
                              hipStream_t stream)
{
    const float* x    = (const float*)d_in[0];
    const float* wq   = (const float*)d_in[1];
    const float* wk   = (const float*)d_in[2];
    const float* wv   = (const float*)d_in[3];
    const float* wo   = (const float*)d_in[4];
    const float* ln1g = (const float*)d_in[5];
    const float* ln1b = (const float*)d_in[6];
    const float* w1   = (const float*)d_in[7];
    const float* b1   = (const float*)d_in[8];
    const float* w2   = (const float*)d_in[9];
    const float* b2   = (const float*)d_in[10];
    const float* ln2g = (const float*)d_in[11];
    const float* ln2b = (const float*)d_in[12];
    float* out = (float*)d_out;

    float* ws = (float*)d_ws;
    float* qb       = ws;
    float* kb       = ws + 4194304;
    float* vb       = ws + 8388608;
    float* pre2     = ws + 12582912;
    float* attn_tmp = ws;
    float* h1       = ws + 4194304;
    float* sbuf     = ws + 8388608;
    float* ffn_tmp  = ws;

    // 1) q,k,v projections: per (b,h): x(2048x1024) @ w[h](1024x64)
    dim3 gqkv(1, Cn / 128, Bn * Hn);
    gemm_t<false, false><<<gqkv, 256, 0, stream>>>(
        x, wq, nullptr, qb, Mn, Mn, Kn, Kn,
        Hn, (long)Cn * Mn, Hn, (long)Mn * Kn, (long)Cn * Kn);
    gemm_t<false, false><<<gqkv, 256, 0, stream>>>(
        x, wk, nullptr, kb, Mn, Mn, Kn, Kn,
        Hn, (long)Cn * Mn, Hn, (long)Mn * Kn, (long)Cn * Kn);
    gemm_t<false, false><<<gqkv, 256, 0, stream>>>(
        x, wv, nullptr, vb, Mn, Mn, Vn, Vn,
        Hn, (long)Cn * Mn, Hn, (long)Mn * Vn, (long)Cn * Vn);

    // 2) flash attention -> pre2 (B*C, H*V)
    attn_flash<<<dim3(Cn / 64, Bn * Hn), 256, 0, stream>>>(qb, kb, vb, pre2);

    // 3) attn_out = pre2 @ wo_flat(1024x1024)
    gemm_t<false, false><<<dim3(Mn / 64, (Bn * Cn) / 128, 1), 256, 0, stream>>>(
        pre2, wo, nullptr, attn_tmp, Mn, Mn, Mn, Mn, 1, 0, 1, 0, 0);

    // 4) h1 = LN(x + attn_out)
    ln_res<<<Bn * Cn, 256, 0, stream>>>(x, attn_tmp, ln1g, ln1b, h1);

    // 5) s = relu(h1 @ w1 + b1)
    gemm_t<true, true><<<dim3(FFn / 64, (Bn * Cn) / 128, 1), 256, 0, stream>>>(
        h1, w1, b1, sbuf, Mn, Mn, FFn, FFn, 1, 0, 1, 0, 0);

    // 6) ffn = s @ w2 + b2
    gemm_t<false, true><<<dim3(Mn / 64, (Bn * Cn) / 128, 1), 256, 0, stream>>>(
        sbuf, w2, b2, ffn_tmp, FFn, FFn, Mn, Mn, 1, 0, 1, 0, 0);

    // 7) out = LN(h1 + ffn)
    ln_res<<<Bn * Cn, 256, 0, stream>>>(h1, ffn_tmp, ln2g, ln2b, out);
}

// Round 5
// 583.090 us; speedup vs baseline: 3.5438x; 3.5438x over previous
//
#include <hip/hip_runtime.h>
#include <hip/hip_bf16.h>

#define Hn 16
#define Mn 1024
#define FFn 4096
#define Bn 2
#define Cn 2048
#define EPSf 1e-5f
#define MB (1024LL*1024LL)

typedef unsigned short u16;
typedef __attribute__((ext_vector_type(8))) short bf16x8;   // 8 bf16 = 4 VGPR
typedef __attribute__((ext_vector_type(4))) float f32x4;
typedef __attribute__((ext_vector_type(8))) unsigned short u16x8;

#define MFMA(a,b,c) __builtin_amdgcn_mfma_f32_16x16x32_bf16(a, b, c, 0, 0, 0)

__device__ __forceinline__ u16 f2b(float v) {          // fp32 -> bf16 RNE
    union { float f; unsigned int u; } x; x.f = v;
    unsigned int r = x.u + 0x7fffu + ((x.u >> 16) & 1u);
    return (u16)(r >> 16);
}
__device__ __forceinline__ float b2f(u16 b) {
    union { unsigned int u; float f; } x; x.u = ((unsigned int)b) << 16;
    return x.f;
}
// async 16B/lane global->LDS. LDS dest = wave-uniform base + lane*16 (linear).
__device__ __forceinline__ void glds16(const void* g, void* l) {
    __builtin_amdgcn_global_load_lds((const __attribute__((address_space(1))) void*)g,
                                     (__attribute__((address_space(3))) void*)l, 16, 0, 0);
}

// ---------------------------------------------------------------------------
// x (f32) -> hi/lo bf16 pair (elementwise). 8 elems/thread.
// ---------------------------------------------------------------------------
__global__ __launch_bounds__(256) void split_cvt(const float* __restrict__ in,
    u16* __restrict__ hi, u16* __restrict__ lo)
{
    const long i = ((long)blockIdx.x * 256 + threadIdx.x) * 8;
    float4 a = *(const float4*)&in[i];
    float4 b = *(const float4*)&in[i + 4];
    float v[8] = {a.x,a.y,a.z,a.w,b.x,b.y,b.z,b.w};
    u16x8 h, l;
#pragma unroll
    for (int j = 0; j < 8; ++j) {
        u16 hh = f2b(v[j]);
        h[j] = hh;
        l[j] = f2b(v[j] - b2f(hh));
    }
    *(u16x8*)&hi[i] = h;
    *(u16x8*)&lo[i] = l;
}

// ---------------------------------------------------------------------------
// Transpose + convert: in f32 (batch,R,C) -> out bf16 (batch,C,R), opt. lo.
// 64x64 tiles, grid (C/64, R/64, batch).
// ---------------------------------------------------------------------------
template<bool SPLIT>
__global__ __launch_bounds__(256) void tcvt(const float* __restrict__ in,
    u16* __restrict__ outh, u16* __restrict__ outl, int R, int Cc)
{
    __shared__ float ts[64][65];
    const int t = threadIdx.x;
    const long ib = (long)blockIdx.z * R * Cc;
    const int r0 = blockIdx.y * 64, c0 = blockIdx.x * 64;
    const int rr = t >> 2, cb = (t & 3) * 16;
#pragma unroll
    for (int u = 0; u < 4; ++u) {
        float4 v = *(const float4*)&in[ib + (long)(r0 + rr) * Cc + c0 + cb + u * 4];
        ts[rr][cb + u*4 + 0] = v.x; ts[rr][cb + u*4 + 1] = v.y;
        ts[rr][cb + u*4 + 2] = v.z; ts[rr][cb + u*4 + 3] = v.w;
    }
    __syncthreads();
    const int oc = t >> 2;
#pragma unroll
    for (int u = 0; u < 4; ++u) {
        float vv[4];
#pragma unroll
        for (int j = 0; j < 4; ++j) vv[j] = ts[cb + u*4 + j][oc];
        ushort4 hh;
        hh.x = f2b(vv[0]); hh.y = f2b(vv[1]); hh.z = f2b(vv[2]); hh.w = f2b(vv[3]);
        *(ushort4*)&outh[ib + (long)(c0 + oc) * R + r0 + cb + u*4] = hh;
        if (SPLIT) {
            ushort4 ll;
            ll.x = f2b(vv[0] - b2f(hh.x)); ll.y = f2b(vv[1] - b2f(hh.y));
            ll.z = f2b(vv[2] - b2f(hh.z)); ll.w = f2b(vv[3] - b2f(hh.w));
            *(ushort4*)&outl[ib + (long)(c0 + oc) * R + r0 + cb + u*4] = ll;
        }
    }
}

// ---------------------------------------------------------------------------
// bf16 transpose: in (batch,R,C) -> out (batch,C,R). grid (C/64, R/64, batch).
// ---------------------------------------------------------------------------
__global__ __launch_bounds__(256) void ttrans(const u16* __restrict__ in,
    u16* __restrict__ out, int R, int Cc)
{
    __shared__ u16 ts[64][72];
    const int t = threadIdx.x;
    const long ib = (long)blockIdx.z * R * Cc;
    const int r0 = blockIdx.y * 64, c0 = blockIdx.x * 64;
    const int rr = t >> 2, cb = (t & 3) * 16;
#pragma unroll
    for (int u = 0; u < 2; ++u)
        *(u16x8*)&ts[rr][cb + u*8] =
            *(const u16x8*)&in[ib + (long)(r0 + rr) * Cc + c0 + cb + u*8];
    __syncthreads();
    const int oc = t >> 2;
#pragma unroll
    for (int u = 0; u < 4; ++u) {
        ushort4 p;
        p.x = ts[cb + u*4 + 0][oc]; p.y = ts[cb + u*4 + 1][oc];
        p.z = ts[cb + u*4 + 2][oc]; p.w = ts[cb + u*4 + 3][oc];
        *(ushort4*)&out[ib + (long)(c0 + oc) * R + r0 + cb + u*4] = p;
    }
}

// ---------------------------------------------------------------------------
// bf16 MFMA GEMM, BM=128 BN=128 BK=32, 4 waves (2x2), wave-tile 64x64.
// A (rows,K) bf16 row-major; Bt (N,K) bf16 row-major (i.e. B transposed).
// ---------------------------------------------------------------------------
template<bool OUTB16, bool BIAS, bool RELU>
__global__ __launch_bounds__(256) void gemm128(
    const u16* __restrict__ A, const u16* __restrict__ Bt,
    const float* __restrict__ bias, void* __restrict__ Cout,
    int Kdim, int lda, int ldbt, int ldc)
{
    __shared__ u16 Als[128*32];
    __shared__ u16 Bls[128*32];
    const int t = threadIdx.x, w = t >> 6, l = t & 63;
    const int wm = w >> 1, wn = w & 1;
    const long row0 = (long)blockIdx.y * 128;
    const int n0 = blockIdx.x * 128;
    const int sr = l >> 2, sc = (l & 3) * 8;
    f32x4 acc[4][4] = {};
    for (int k0 = 0; k0 < Kdim; k0 += 32) {
        __syncthreads();
#pragma unroll
        for (int i = 0; i < 2; ++i) {
            const int c = w*2 + i;   // chunks 0..7 (A) and 0..7 (B)
            glds16(&A[(row0 + c*16 + sr) * lda + k0 + sc], (char*)Als + c*1024);
            glds16(&Bt[((long)n0 + c*16 + sr) * ldbt + k0 + sc], (char*)Bls + c*1024);
        }
        __syncthreads();
        bf16x8 af[4], bfv[4];
#pragma unroll
        for (int mf = 0; mf < 4; ++mf)
            af[mf] = *(const bf16x8*)&Als[(wm*64 + mf*16 + (l&15))*32 + (l>>4)*8];
#pragma unroll
        for (int nf = 0; nf < 4; ++nf)
            bfv[nf] = *(const bf16x8*)&Bls[(wn*64 + nf*16 + (l&15))*32 + (l>>4)*8];
#pragma unroll
        for (int mf = 0; mf < 4; ++mf)
#pragma unroll
            for (int nf = 0; nf < 4; ++nf)
                acc[mf][nf] = MFMA(af[mf], bfv[nf], acc[mf][nf]);
    }
#pragma unroll
    for (int nf = 0; nf < 4; ++nf) {
        const int col = n0 + wn*64 + nf*16 + (l & 15);
        const float bv = BIAS ? bias[col] : 0.f;
#pragma unroll
        for (int mf = 0; mf < 4; ++mf)
#pragma unroll
            for (int r = 0; r < 4; ++r) {
                const long row = row0 + wm*64 + mf*16 + (l>>4)*4 + r;
                float v = acc[mf][nf][r] + bv;
                if (RELU) v = fmaxf(v, 0.f);
                if (OUTB16) ((u16*)Cout)[row * ldc + col] = f2b(v);
                else        ((float*)Cout)[row * ldc + col] = v;
            }
    }
}

// ---------------------------------------------------------------------------
// Batched bf16 GEMM, BM=128 BN=64 BK=32, out ldc=64 fixed. Optional split
// input (Ah+Al, Bh+Bl: acc = Ah*Bh + Ah*Bl + Al*Bh) and split output
// (hi/lo bf16 of scale*acc). Used for q/k/v projections (per-head weights).
// ---------------------------------------------------------------------------
template<bool SIN, bool SOUT>
__global__ __launch_bounds__(256) void gemm64(
    const u16* __restrict__ Ah, const u16* __restrict__ Alo,
    const u16* __restrict__ Bth, const u16* __restrict__ Btl,
    u16* __restrict__ Chi, u16* __restrict__ Clo, float scale,
    int Kdim, int lda, int ldbt,
    int aDiv, long aStride, int bMod, long bStride, long cStride)
{
    extern __shared__ u16 lds[];
    u16* AH = lds;              // [128][32]
    u16* BH = lds + 4096;       // [64][32]
    u16* AL = lds + 6144;
    u16* BL = lds + 10240;
    const int t = threadIdx.x, w = t >> 6, l = t & 63;
    const int wm = w >> 1, wn = w & 1;
    const int z = blockIdx.z;
    const u16* Ahb = Ah + (long)(z / aDiv) * aStride;
    const u16* Alb = SIN ? (Alo + (long)(z / aDiv) * aStride) : (const u16*)nullptr;
    const u16* Bhb = Bth + (long)(z % bMod) * bStride;
    const u16* Blb = SIN ? (Btl + (long)(z % bMod) * bStride) : (const u16*)nullptr;
    const long row0 = (long)blockIdx.y * 128;
    const int sr = l >> 2, sc = (l & 3) * 8;
    f32x4 acc[4][2] = {};
    const int NCH = SIN ? 6 : 3;
    for (int k0 = 0; k0 < Kdim; k0 += 32) {
        __syncthreads();
        for (int i = 0; i < NCH; ++i) {
            const int idx = w + i*4;   // wave-uniform
            if (idx < 8)
                glds16(&Ahb[(row0 + idx*16 + sr)*lda + k0 + sc], (char*)AH + idx*1024);
            else if (idx < 12)
                glds16(&Bhb[(long)((idx-8)*16 + sr)*ldbt + k0 + sc], (char*)BH + (idx-8)*1024);
            else if (idx < 20)
                glds16(&Alb[(row0 + (idx-12)*16 + sr)*lda + k0 + sc], (char*)AL + (idx-12)*1024);
            else
                glds16(&Blb[(long)((idx-20)*16 + sr)*ldbt + k0 + sc], (char*)BL + (idx-20)*1024);
        }
        __syncthreads();
        bf16x8 ah[4], bh[2], al[4], bl[2];
#pragma unroll
        for (int mf = 0; mf < 4; ++mf)
            ah[mf] = *(const bf16x8*)&AH[(wm*64 + mf*16 + (l&15))*32 + (l>>4)*8];
#pragma unroll
        for (int nf = 0; nf < 2; ++nf)
            bh[nf] = *(const bf16x8*)&BH[(wn*32 + nf*16 + (l&15))*32 + (l>>4)*8];
        if (SIN) {
#pragma unroll
            for (int mf = 0; mf < 4; ++mf)
                al[mf] = *(const bf16x8*)&AL[(wm*64 + mf*16 + (l&15))*32 + (l>>4)*8];
#pragma unroll
            for (int nf = 0; nf < 2; ++nf)
                bl[nf] = *(const bf16x8*)&BL[(wn*32 + nf*16 + (l&15))*32 + (l>>4)*8];
        }
#pragma unroll
        for (int mf = 0; mf < 4; ++mf)
#pragma unroll
            for (int nf = 0; nf < 2; ++nf) {
                acc[mf][nf] = MFMA(ah[mf], bh[nf], acc[mf][nf]);
                if (SIN) {
                    acc[mf][nf] = MFMA(ah[mf], bl[nf], acc[mf][nf]);
                    acc[mf][nf] = MFMA(al[mf], bh[nf], acc[mf][nf]);
                }
            }
    }
    u16* Cb  = Chi + (long)z * cStride;
    u16* Clb = SOUT ? (Clo + (long)z * cStride) : (u16*)nullptr;
#pragma unroll
    for (int mf = 0; mf < 4; ++mf)
#pragma unroll
        for (int nf = 0; nf < 2; ++nf)
#pragma unroll
            for (int r = 0; r < 4; ++r) {
                const long row = row0 + wm*64 + mf*16 + (l>>4)*4 + r;
                const int col = wn*32 + nf*16 + (l & 15);
                const float v = acc[mf][nf][r] * scale;
                const u16 hh = f2b(v);
                Cb[row*64 + col] = hh;
                if (SOUT) Clb[row*64 + col] = f2b(v - b2f(hh));
            }
}

// ---------------------------------------------------------------------------
// Flash attention, MFMA. Block = (b,h) x 64 queries, 4 waves, wave owns 16 q.
// Scores = (qh+ql)(kh+kl) via 3 MFMAs (split bf16, fp32-grade). PV in bf16.
// K/V/Q LDS tiles XOR-swizzled (chunk ^= row&7) via pre-swizzled global src.
// q_hi/q_lo are pre-scaled by 0.125. Output pre2b: [(b,q)][h*64+v] bf16.
// ---------------------------------------------------------------------------
__global__ __launch_bounds__(256) void attn_mfma(
    const u16* __restrict__ qh, const u16* __restrict__ ql,
    const u16* __restrict__ kh, const u16* __restrict__ kl,
    const u16* __restrict__ vt, u16* __restrict__ pre2b)
{
    __shared__ u16 QH[4096], QL[4096], KH[4096], KL[4096], VT[4096];
    __shared__ u16 PL[4][1152];   // per-wave P tile [16][72]
    const int t = threadIdx.x, w = t >> 6, l = t & 63;
    const int bh = blockIdx.y, b = bh >> 4, h = bh & 15;
    const int q0 = blockIdx.x * 64;
    const long base = (long)bh * Cn * 64;
    const int srow = l >> 3;                 // row within 8-row chunk
    const int gch  = (l & 7) ^ (l >> 3);     // pre-swizzled global 16B-chunk

    // stage Q hi/lo (swizzled), chunks i = w*2, w*2+1 of 8
#pragma unroll
    for (int i = 0; i < 2; ++i) {
        const int ci = w*2 + i;
        const int row = ci*8 + srow;
        glds16(&qh[base + (long)(q0 + row)*64 + gch*8], (char*)QH + ci*1024);
        glds16(&ql[base + (long)(q0 + row)*64 + gch*8], (char*)QL + ci*1024);
    }
    __syncthreads();
    bf16x8 qfh[2], qfl[2];
#pragma unroll
    for (int ks = 0; ks < 2; ++ks) {
        const int row = w*16 + (l & 15);
        const int ch = ((l>>4) + ks*4) ^ (row & 7);
        qfh[ks] = *(const bf16x8*)&QH[row*64 + ch*8];
        qfl[ks] = *(const bf16x8*)&QL[row*64 + ch*8];
    }
    float m_[4], ls_[4];
    f32x4 o[4] = {};
#pragma unroll
    for (int r = 0; r < 4; ++r) { m_[r] = -1e30f; ls_[r] = 0.f; }

    for (int c0 = 0; c0 < Cn; c0 += 64) {
        __syncthreads();   // prev tile fully consumed
#pragma unroll
        for (int i = 0; i < 2; ++i) {
            const int ci = w*2 + i;
            const int row = ci*8 + srow;
            glds16(&kh[base + (long)(c0 + row)*64 + gch*8], (char*)KH + ci*1024);
            glds16(&kl[base + (long)(c0 + row)*64 + gch*8], (char*)KL + ci*1024);
            glds16(&vt[base + (long)row*Cn + c0 + gch*8],   (char*)VT + ci*1024);
        }
        __syncthreads();
        // scores: wave computes S[16q][64c]; D-frag row=(l>>4)*4+r, col=l&15
        f32x4 sc[4];
#pragma unroll
        for (int cf = 0; cf < 4; ++cf) {
            f32x4 a = {0.f, 0.f, 0.f, 0.f};
#pragma unroll
            for (int ks = 0; ks < 2; ++ks) {
                const int row = cf*16 + (l & 15);
                const int ch = ((l>>4) + ks*4) ^ (row & 7);
                const bf16x8 kfh = *(const bf16x8*)&KH[row*64 + ch*8];
                const bf16x8 kfl = *(const bf16x8*)&KL[row*64 + ch*8];
                a = MFMA(qfh[ks], kfh, a);
                a = MFMA(qfh[ks], kfl, a);
                a = MFMA(qfl[ks], kfh, a);
            }
            sc[cf] = a;
        }
        // online softmax per q-row (row lives in one 16-lane group)
        float mx[4];
#pragma unroll
        for (int r = 0; r < 4; ++r)
            mx[r] = fmaxf(fmaxf(sc[0][r], sc[1][r]), fmaxf(sc[2][r], sc[3][r]));
#pragma unroll
        for (int off = 1; off < 16; off <<= 1)
#pragma unroll
            for (int r = 0; r < 4; ++r)
                mx[r] = fmaxf(mx[r], __shfl_xor(mx[r], off, 64));
        float fct[4], rs_[4];
#pragma unroll
        for (int r = 0; r < 4; ++r) {
            const float mn = fmaxf(m_[r], mx[r]);
            fct[r] = __expf(m_[r] - mn);
            m_[r] = mn;
            rs_[r] = 0.f;
        }
#pragma unroll
        for (int cf = 0; cf < 4; ++cf)
#pragma unroll
            for (int r = 0; r < 4; ++r) {
                const float p = __expf(sc[cf][r] - m_[r]);
                rs_[r] += p;
                PL[w][((l>>4)*4 + r)*72 + cf*16 + (l & 15)] = f2b(p);
            }
#pragma unroll
        for (int off = 1; off < 16; off <<= 1)
#pragma unroll
            for (int r = 0; r < 4; ++r)
                rs_[r] += __shfl_xor(rs_[r], off, 64);
#pragma unroll
        for (int r = 0; r < 4; ++r)
            ls_[r] = ls_[r] * fct[r] + rs_[r];
        // rescale O, then O += P*V
#pragma unroll
        for (int vf = 0; vf < 4; ++vf)
#pragma unroll
            for (int r = 0; r < 4; ++r)
                o[vf][r] *= fct[r];
        bf16x8 pa[2];
#pragma unroll
        for (int ks = 0; ks < 2; ++ks)
            pa[ks] = *(const bf16x8*)&PL[w][(l&15)*72 + ks*32 + (l>>4)*8];
#pragma unroll
        for (int vf = 0; vf < 4; ++vf)
#pragma unroll
            for (int ks = 0; ks < 2; ++ks) {
                const int row = vf*16 + (l & 15);
                const int ch = ((l>>4) + ks*4) ^ (row & 7);
                const bf16x8 vfr = *(const bf16x8*)&VT[row*64 + ch*8];
                o[vf] = MFMA(pa[ks], vfr, o[vf]);
            }
    }
    float inv[4];
#pragma unroll
    for (int r = 0; r < 4; ++r) inv[r] = 1.f / ls_[r];
#pragma unroll
    for (int vf = 0; vf < 4; ++vf)
#pragma unroll
        for (int r = 0; r < 4; ++r) {
            const long q = q0 + w*16 + (l>>4)*4 + r;
            pre2b[((long)b*Cn + q)*1024 + h*64 + vf*16 + (l&15)] = f2b(o[vf][r] * inv[r]);
        }
}

// ---------------------------------------------------------------------------
// Fused residual + LayerNorm; optional bf16 twin output.
// ---------------------------------------------------------------------------
template<bool WB16>
__global__ __launch_bounds__(256) void ln_res(
    const float* __restrict__ a, const float* __restrict__ r,
    const float* __restrict__ g, const float* __restrict__ be,
    float* __restrict__ out, u16* __restrict__ outb)
{
    __shared__ float wsum[4];
    __shared__ float wsum2[4];
    const long row = blockIdx.x;
    const int t = threadIdx.x;
    float4 va = *(const float4*)&a[row * Mn + t * 4];
    float4 vb = *(const float4*)&r[row * Mn + t * 4];
    float v0 = va.x + vb.x, v1 = va.y + vb.y, v2 = va.z + vb.z, v3 = va.w + vb.w;

    float s = v0 + v1 + v2 + v3;
#pragma unroll
    for (int off = 32; off > 0; off >>= 1) s += __shfl_xor(s, off, 64);
    if ((t & 63) == 0) wsum[t >> 6] = s;
    __syncthreads();
    float mu = (wsum[0] + wsum[1] + wsum[2] + wsum[3]) * (1.0f / Mn);

    float d0 = v0 - mu, d1 = v1 - mu, d2 = v2 - mu, d3 = v3 - mu;
    float s2 = d0 * d0 + d1 * d1 + d2 * d2 + d3 * d3;
#pragma unroll
    for (int off = 32; off > 0; off >>= 1) s2 += __shfl_xor(s2, off, 64);
    if ((t & 63) == 0) wsum2[t >> 6] = s2;
    __syncthreads();
    float var = (wsum2[0] + wsum2[1] + wsum2[2] + wsum2[3]) * (1.0f / Mn);
    float rstd = rsqrtf(var + EPSf);

    float4 g4 = *(const float4*)&g[t * 4];
    float4 b4 = *(const float4*)&be[t * 4];
    float4 r4;
    r4.x = d0 * rstd * g4.x + b4.x;
    r4.y = d1 * rstd * g4.y + b4.y;
    r4.z = d2 * rstd * g4.z + b4.z;
    r4.w = d3 * rstd * g4.w + b4.w;
    *(float4*)&out[row * Mn + t * 4] = r4;
    if (WB16) {
        ushort4 ob;
        ob.x = f2b(r4.x); ob.y = f2b(r4.y); ob.z = f2b(r4.z); ob.w = f2b(r4.w);
        *(ushort4*)&outb[row * Mn + t * 4] = ob;
    }
}

// ---------------------------------------------------------------------------
// Orchestration. Workspace byte offsets (MB), peak 84MB:
//  x_hi 0, x_lo 8, wqT_h 16, wqT_l 18, wkT_h 20, wkT_l 22, wvT 24, woT 26,
//  q_hi 28, q_lo 36, k_hi 44, k_lo 52, vb 60, vTb 68, pre2b 76
//  then (reuse): attn_tmp 28(f32), h1 44(f32), h1b 60, w1T 68, w2T 76,
//  sbuf 0(32MB bf16), ffn 60(f32)
// ---------------------------------------------------------------------------
extern "C" void kernel_launch(void* const* d_in, const int* in_sizes, int n_in,
                              void* d_out, int out_size, void* d_ws, size_t ws_size,
                              hipStream_t stream)
{
    const float* x    = (const float*)d_in[0];
    const float* wq   = (const float*)d_in[1];
    const float* wk   = (const float*)d_in[2];
    const float* wv   = (const float*)d_in[3];
    const float* wo   = (const float*)d_in[4];
    const float* ln1g = (const float*)d_in[5];
    const float* ln1b = (const float*)d_in[6];
    const float* w1   = (const float*)d_in[7];
    const float* b1   = (const float*)d_in[8];
    const float* w2   = (const float*)d_in[9];
    const float* b2   = (const float*)d_in[10];
    const float* ln2g = (const float*)d_in[11];
    const float* ln2b = (const float*)d_in[12];
    float* out = (float*)d_out;

    char* W = (char*)d_ws;
    u16* x_hi  = (u16*)(W + 0*MB);
    u16* x_lo  = (u16*)(W + 8*MB);
    u16* wqTh  = (u16*)(W + 16*MB);
    u16* wqTl  = (u16*)(W + 18*MB);
    u16* wkTh  = (u16*)(W + 20*MB);
    u16* wkTl  = (u16*)(W + 22*MB);
    u16* wvT   = (u16*)(W + 24*MB);
    u16* woT   = (u16*)(W + 26*MB);
    u16* q_hi  = (u16*)(W + 28*MB);
    u16* q_lo  = (u16*)(W + 36*MB);
    u16* k_hi  = (u16*)(W + 44*MB);
    u16* k_lo  = (u16*)(W + 52*MB);
    u16* vb    = (u16*)(W + 60*MB);
    u16* vTb   = (u16*)(W + 68*MB);
    u16* pre2b = (u16*)(W + 76*MB);
    float* attn_tmp = (float*)(W + 28*MB);
    float* h1  = (float*)(W + 44*MB);
    u16* h1b   = (u16*)(W + 60*MB);
    u16* w1T   = (u16*)(W + 68*MB);
    u16* w2T   = (u16*)(W + 76*MB);
    u16* sbuf  = (u16*)(W + 0*MB);
    float* ffn = (float*)(W + 60*MB);

    const long CM = (long)Cn * Mn;      // x per-batch stride
    const long WS = 64LL * 1024;        // per-head weight stride
    const long CS = (long)Cn * 64;      // per-(b,h) q/k/v stride

    // 1) conversions
    split_cvt<<<2048, 256, 0, stream>>>(x, x_hi, x_lo);
    tcvt<true ><<<dim3(1,16,16), 256, 0, stream>>>(wq, wqTh, wqTl, 1024, 64);
    tcvt<true ><<<dim3(1,16,16), 256, 0, stream>>>(wk, wkTh, wkTl, 1024, 64);
    tcvt<false><<<dim3(1,16,16), 256, 0, stream>>>(wv, wvT, nullptr, 1024, 64);
    tcvt<false><<<dim3(16,16,1), 256, 0, stream>>>(wo, woT, nullptr, 1024, 1024);

    // 2) projections: q (scaled 1/8, split), k (split), v (plain bf16)
    gemm64<true,true ><<<dim3(1,16,32), 256, 24576, stream>>>(
        x_hi, x_lo, wqTh, wqTl, q_hi, q_lo, 0.125f, 1024, 1024, 1024, 16, CM, 16, WS, CS);
    gemm64<true,true ><<<dim3(1,16,32), 256, 24576, stream>>>(
        x_hi, x_lo, wkTh, wkTl, k_hi, k_lo, 1.0f,   1024, 1024, 1024, 16, CM, 16, WS, CS);
    gemm64<false,false><<<dim3(1,16,32), 256, 12288, stream>>>(
        x_hi, nullptr, wvT, nullptr, vb, nullptr, 1.0f, 1024, 1024, 1024, 16, CM, 16, WS, CS);
    ttrans<<<dim3(1,32,32), 256, 0, stream>>>(vb, vTb, 2048, 64);

    // 3) flash attention -> pre2b (B*C, H*V) bf16
    attn_mfma<<<dim3(32,32), 256, 0, stream>>>(q_hi, q_lo, k_hi, k_lo, vTb, pre2b);

    // 4) late weight transposes into freed regions
    tcvt<false><<<dim3(64,16,1), 256, 0, stream>>>(w1, w1T, nullptr, 1024, 4096);

    // 5) attn_out = pre2b @ woT^T -> f32
    gemm128<false,false,false><<<dim3(8,32), 256, 0, stream>>>(
        pre2b, woT, nullptr, attn_tmp, 1024, 1024, 1024, 1024);
    tcvt<false><<<dim3(16,64,1), 256, 0, stream>>>(w2, w2T, nullptr, 4096, 1024);

    // 6) h1 = LN(x + attn_out) -> f32 + bf16
    ln_res<true ><<<Bn*Cn, 256, 0, stream>>>(x, attn_tmp, ln1g, ln1b, h1, h1b);

    // 7) s = relu(h1 @ w1 + b1) -> bf16
    gemm128<true,true,true ><<<dim3(32,32), 256, 0, stream>>>(
        h1b, w1T, b1, sbuf, 1024, 1024, 1024, 4096);

    // 8) ffn = s @ w2 + b2 -> f32
    gemm128<false,true,false><<<dim3(8,32), 256, 0, stream>>>(
        sbuf, w2T, b2, ffn, 4096, 4096, 4096, 1024);

    // 9) out = LN(h1 + ffn)
    ln_res<false><<<Bn*Cn, 256, 0, stream>>>(h1, ffn, ln2g, ln2b, out, nullptr);
}

// Round 7
// 550.721 us; speedup vs baseline: 3.7521x; 1.0588x over previous
//
#include <hip/hip_runtime.h>
#include <hip/hip_bf16.h>

#define Hn 16
#define Mn 1024
#define FFn 4096
#define Bn 2
#define Cn 2048
#define EPSf 1e-5f
#define MB (1024LL*1024LL)

typedef unsigned short u16;
typedef __attribute__((ext_vector_type(8))) short bf16x8;   // 8 bf16 = 4 VGPR
typedef __attribute__((ext_vector_type(4))) float f32x4;
typedef __attribute__((ext_vector_type(8))) unsigned short u16x8;

#define MFMA(a,b,c) __builtin_amdgcn_mfma_f32_16x16x32_bf16(a, b, c, 0, 0, 0)

__device__ __forceinline__ u16 f2b(float v) {          // fp32 -> bf16 RNE
    union { float f; unsigned int u; } x; x.f = v;
    unsigned int r = x.u + 0x7fffu + ((x.u >> 16) & 1u);
    return (u16)(r >> 16);
}
__device__ __forceinline__ float b2f(u16 b) {
    union { unsigned int u; float f; } x; x.u = ((unsigned int)b) << 16;
    return x.f;
}
// async 16B/lane global->LDS. LDS dest = wave-uniform base + lane*16 (linear).
__device__ __forceinline__ void glds16(const void* g, void* l) {
    __builtin_amdgcn_global_load_lds((const __attribute__((address_space(1))) void*)g,
                                     (__attribute__((address_space(3))) void*)l, 16, 0, 0);
}

// ---------------------------------------------------------------------------
// x (f32) -> hi/lo bf16 pair (elementwise). 8 elems/thread.
// ---------------------------------------------------------------------------
__global__ __launch_bounds__(256) void split_cvt(const float* __restrict__ in,
    u16* __restrict__ hi, u16* __restrict__ lo)
{
    const long i = ((long)blockIdx.x * 256 + threadIdx.x) * 8;
    float4 a = *(const float4*)&in[i];
    float4 b = *(const float4*)&in[i + 4];
    float v[8] = {a.x,a.y,a.z,a.w,b.x,b.y,b.z,b.w};
    u16x8 h, l;
#pragma unroll
    for (int j = 0; j < 8; ++j) {
        u16 hh = f2b(v[j]);
        h[j] = hh;
        l[j] = f2b(v[j] - b2f(hh));
    }
    *(u16x8*)&hi[i] = h;
    *(u16x8*)&lo[i] = l;
}

// ---------------------------------------------------------------------------
// Transpose + convert: in f32 (batch,R,C) -> out bf16 (batch,C,R), opt. lo.
// 64x64 tiles, grid (C/64, R/64, batch).
// ---------------------------------------------------------------------------
template<bool SPLIT>
__global__ __launch_bounds__(256) void tcvt(const float* __restrict__ in,
    u16* __restrict__ outh, u16* __restrict__ outl, int R, int Cc)
{
    __shared__ float ts[64][65];
    const int t = threadIdx.x;
    const long ib = (long)blockIdx.z * R * Cc;
    const int r0 = blockIdx.y * 64, c0 = blockIdx.x * 64;
    const int rr = t >> 2, cb = (t & 3) * 16;
#pragma unroll
    for (int u = 0; u < 4; ++u) {
        float4 v = *(const float4*)&in[ib + (long)(r0 + rr) * Cc + c0 + cb + u * 4];
        ts[rr][cb + u*4 + 0] = v.x; ts[rr][cb + u*4 + 1] = v.y;
        ts[rr][cb + u*4 + 2] = v.z; ts[rr][cb + u*4 + 3] = v.w;
    }
    __syncthreads();
    const int oc = t >> 2;
#pragma unroll
    for (int u = 0; u < 4; ++u) {
        float vv[4];
#pragma unroll
        for (int j = 0; j < 4; ++j) vv[j] = ts[cb + u*4 + j][oc];
        ushort4 hh;
        hh.x = f2b(vv[0]); hh.y = f2b(vv[1]); hh.z = f2b(vv[2]); hh.w = f2b(vv[3]);
        *(ushort4*)&outh[ib + (long)(c0 + oc) * R + r0 + cb + u*4] = hh;
        if (SPLIT) {
            ushort4 ll;
            ll.x = f2b(vv[0] - b2f(hh.x)); ll.y = f2b(vv[1] - b2f(hh.y));
            ll.z = f2b(vv[2] - b2f(hh.z)); ll.w = f2b(vv[3] - b2f(hh.w));
            *(ushort4*)&outl[ib + (long)(c0 + oc) * R + r0 + cb + u*4] = ll;
        }
    }
}

// ---------------------------------------------------------------------------
// V transpose: vb (B*C, H*64) bf16 -> vTb (B*H, 64, C). grid (C/64, 1, B*H).
// ---------------------------------------------------------------------------
__global__ __launch_bounds__(256) void ttrans2(const u16* __restrict__ in,
    u16* __restrict__ out)
{
    __shared__ u16 ts[64][72];
    const int t = threadIdx.x;
    const int bh = blockIdx.z, b = bh >> 4, h = bh & 15;
    const int c0 = blockIdx.x * 64;
    const int rr = t >> 2, cb = (t & 3) * 16;   // rr = c-row, cb = d-col base
#pragma unroll
    for (int u = 0; u < 2; ++u)
        *(u16x8*)&ts[rr][cb + u*8] =
            *(const u16x8*)&in[((long)b*Cn + c0 + rr) * 1024 + h*64 + cb + u*8];
    __syncthreads();
    const int oc = t >> 2;   // d index
#pragma unroll
    for (int u = 0; u < 4; ++u) {
        ushort4 p;
        p.x = ts[cb + u*4 + 0][oc]; p.y = ts[cb + u*4 + 1][oc];
        p.z = ts[cb + u*4 + 2][oc]; p.w = ts[cb + u*4 + 3][oc];
        *(ushort4*)&out[(long)bh*64*Cn + (long)oc*Cn + c0 + cb + u*4] = p;
    }
}

// ---------------------------------------------------------------------------
// bf16 MFMA GEMM, BM=128 BN=128 BK=32, 4 waves (2x2), wave-tile 64x64.
// A (rows,K) row-major; Bt (N,K) row-major (B transposed).
// SIN: split inputs (acc = Ah*Bh + Ah*Bl + Al*Bh, 3 MFMAs).
// SOUT: also write lo-part bf16 of the (scaled) result.
// Per-column scale: col < scol ? s1 : s2 (for fused q||k projection).
// ---------------------------------------------------------------------------
template<bool SIN, bool SOUT, bool OUTB16, bool BIAS, bool RELU>
__global__ __launch_bounds__(256) void gemm128(
    const u16* __restrict__ A, const u16* __restrict__ Al,
    const u16* __restrict__ Bt, const u16* __restrict__ Btl,
    const float* __restrict__ bias, void* __restrict__ Cout,
    u16* __restrict__ Clo, float s1, float s2, int scol,
    int Kdim, int lda, int ldbt, int ldc)
{
    __shared__ u16 lds[SIN ? 16384 : 8192];   // Ah | Bh | Al | Bl, 8KB each
    const int t = threadIdx.x, w = t >> 6, l = t & 63;
    const int wm = w >> 1, wn = w & 1;
    const long row0 = (long)blockIdx.y * 128;
    const int n0 = blockIdx.x * 128;
    const int sr = l >> 2, sc = (l & 3) * 8;
    f32x4 acc[4][4] = {};
    const int NCH = SIN ? 8 : 4;
    for (int k0 = 0; k0 < Kdim; k0 += 32) {
        __syncthreads();
#pragma unroll
        for (int i = 0; i < NCH; ++i) {
            const int idx = w + i*4;   // wave-uniform
            if (idx < 8)
                glds16(&A[(row0 + idx*16 + sr)*lda + k0 + sc], (char*)lds + idx*1024);
            else if (idx < 16)
                glds16(&Bt[((long)n0 + (idx-8)*16 + sr)*ldbt + k0 + sc], (char*)lds + 8192 + (idx-8)*1024);
            else if (idx < 24)
                glds16(&Al[(row0 + (idx-16)*16 + sr)*lda + k0 + sc], (char*)lds + 16384 + (idx-16)*1024);
            else
                glds16(&Btl[((long)n0 + (idx-24)*16 + sr)*ldbt + k0 + sc], (char*)lds + 24576 + (idx-24)*1024);
        }
        __syncthreads();
        bf16x8 af[4], bfv[4], alf[4], blf[4];
#pragma unroll
        for (int mf = 0; mf < 4; ++mf)
            af[mf] = *(const bf16x8*)&lds[(wm*64 + mf*16 + (l&15))*32 + (l>>4)*8];
#pragma unroll
        for (int nf = 0; nf < 4; ++nf)
            bfv[nf] = *(const bf16x8*)&lds[4096 + (wn*64 + nf*16 + (l&15))*32 + (l>>4)*8];
        if (SIN) {
#pragma unroll
            for (int mf = 0; mf < 4; ++mf)
                alf[mf] = *(const bf16x8*)&lds[8192 + (wm*64 + mf*16 + (l&15))*32 + (l>>4)*8];
#pragma unroll
            for (int nf = 0; nf < 4; ++nf)
                blf[nf] = *(const bf16x8*)&lds[12288 + (wn*64 + nf*16 + (l&15))*32 + (l>>4)*8];
        }
#pragma unroll
        for (int mf = 0; mf < 4; ++mf)
#pragma unroll
            for (int nf = 0; nf < 4; ++nf) {
                acc[mf][nf] = MFMA(af[mf], bfv[nf], acc[mf][nf]);
                if (SIN) {
                    acc[mf][nf] = MFMA(af[mf], blf[nf], acc[mf][nf]);
                    acc[mf][nf] = MFMA(alf[mf], bfv[nf], acc[mf][nf]);
                }
            }
    }
#pragma unroll
    for (int nf = 0; nf < 4; ++nf) {
        const int col = n0 + wn*64 + nf*16 + (l & 15);
        const float scf = (col < scol) ? s1 : s2;
        const float bv = BIAS ? bias[col] : 0.f;
#pragma unroll
        for (int mf = 0; mf < 4; ++mf)
#pragma unroll
            for (int r = 0; r < 4; ++r) {
                const long row = row0 + wm*64 + mf*16 + (l>>4)*4 + r;
                float v = acc[mf][nf][r] * scf + bv;
                if (RELU) v = fmaxf(v, 0.f);
                if (OUTB16) {
                    const u16 hh = f2b(v);
                    ((u16*)Cout)[row * ldc + col] = hh;
                    if (SOUT) Clo[row * ldc + col] = f2b(v - b2f(hh));
                } else {
                    ((float*)Cout)[row * ldc + col] = v;
                }
            }
    }
}

// ---------------------------------------------------------------------------
// Flash attention, MFMA. Block = (b,h) x 64 queries, 4 waves, wave owns 16 q.
// q/k packed interleaved: qk[(b*C + t)*2048 + h*64 + d] (+1024 for k), hi/lo.
// Scores = qh*kh + qh*kl + ql*kh (split bf16). PV in bf16.
// LDS 40KB: K/V tiles + Q-prologue region; P tile aliases the Q region
// (safe: every wave's Q ds_reads drain at its barrier-A before any wave
//  passes barrier-B and writes PL). 4 blocks/CU.
// q pre-scaled by 0.125. Output pre2b: [(b,q)][h*64+v] bf16.
// ---------------------------------------------------------------------------
__global__ __launch_bounds__(256) void attn_mfma(
    const u16* __restrict__ qkh, const u16* __restrict__ qkl,
    const u16* __restrict__ vt, u16* __restrict__ pre2b)
{
    __shared__ u16 SH[20480];           // 40 KB
    u16* KH = SH;                        // [64][64]
    u16* KL = SH + 4096;
    u16* VT = SH + 8192;
    u16* QH = SH + 12288;                // prologue only
    u16* QL = SH + 16384;                // prologue only
    u16* PL = SH + 12288;                // aliases QH/QL; 4 waves x [16][72]

    const int t = threadIdx.x, w = t >> 6, l = t & 63;
    const int bh = blockIdx.y, b = bh >> 4, h = bh & 15;
    const int q0 = blockIdx.x * 64;
    const long rbase = (long)b * Cn;        // row base into (B*C, 2048)
    const int hoff = h * 64;
    const long vbase = (long)bh * 64 * Cn;  // vTb per-(b,h) base
    const int srow = l >> 3;                 // row within 8-row chunk
    const int gch  = (l & 7) ^ (l >> 3);     // pre-swizzled global 16B-chunk

    // stage Q hi/lo (swizzled), chunks ci = w*2, w*2+1 of 8
#pragma unroll
    for (int i = 0; i < 2; ++i) {
        const int ci = w*2 + i;
        const int row = ci*8 + srow;
        glds16(&qkh[(rbase + q0 + row)*2048 + hoff + gch*8], (char*)QH + ci*1024);
        glds16(&qkl[(rbase + q0 + row)*2048 + hoff + gch*8], (char*)QL + ci*1024);
    }
    __syncthreads();
    bf16x8 qfh[2], qfl[2];
#pragma unroll
    for (int ks = 0; ks < 2; ++ks) {
        const int row = w*16 + (l & 15);
        const int ch = ((l>>4) + ks*4) ^ (row & 7);
        qfh[ks] = *(const bf16x8*)&QH[row*64 + ch*8];
        qfl[ks] = *(const bf16x8*)&QL[row*64 + ch*8];
    }
    float m_[4], ls_[4];
    f32x4 o[4] = {};
#pragma unroll
    for (int r = 0; r < 4; ++r) { m_[r] = -1e30f; ls_[r] = 0.f; }

    for (int c0 = 0; c0 < Cn; c0 += 64) {
        __syncthreads();   // (A) prev tile fully consumed (also drains Q reads, tile 0)
#pragma unroll
        for (int i = 0; i < 2; ++i) {
            const int ci = w*2 + i;
            const int row = ci*8 + srow;
            glds16(&qkh[(rbase + c0 + row)*2048 + 1024 + hoff + gch*8], (char*)KH + ci*1024);
            glds16(&qkl[(rbase + c0 + row)*2048 + 1024 + hoff + gch*8], (char*)KL + ci*1024);
            glds16(&vt[vbase + (long)row*Cn + c0 + gch*8], (char*)VT + ci*1024);
        }
        __syncthreads();   // (B) tiles loaded
        // scores: wave computes S[16q][64c]; D-frag row=(l>>4)*4+r, col=l&15
        f32x4 scv[4];
#pragma unroll
        for (int cf = 0; cf < 4; ++cf) {
            f32x4 a = {0.f, 0.f, 0.f, 0.f};
#pragma unroll
            for (int ks = 0; ks < 2; ++ks) {
                const int row = cf*16 + (l & 15);
                const int ch = ((l>>4) + ks*4) ^ (row & 7);
                const bf16x8 kfh = *(const bf16x8*)&KH[row*64 + ch*8];
                const bf16x8 kfl = *(const bf16x8*)&KL[row*64 + ch*8];
                a = MFMA(qfh[ks], kfh, a);
                a = MFMA(qfh[ks], kfl, a);
                a = MFMA(qfl[ks], kfh, a);
            }
            scv[cf] = a;
        }
        // online softmax per q-row (row lives in one 16-lane group)
        float mx[4];
#pragma unroll
        for (int r = 0; r < 4; ++r)
            mx[r] = fmaxf(fmaxf(scv[0][r], scv[1][r]), fmaxf(scv[2][r], scv[3][r]));
#pragma unroll
        for (int off = 1; off < 16; off <<= 1)
#pragma unroll
            for (int r = 0; r < 4; ++r)
                mx[r] = fmaxf(mx[r], __shfl_xor(mx[r], off, 64));
        float fct[4], rs_[4];
#pragma unroll
        for (int r = 0; r < 4; ++r) {
            const float mn = fmaxf(m_[r], mx[r]);
            fct[r] = __expf(m_[r] - mn);
            m_[r] = mn;
            rs_[r] = 0.f;
        }
#pragma unroll
        for (int cf = 0; cf < 4; ++cf)
#pragma unroll
            for (int r = 0; r < 4; ++r) {
                const float p = __expf(scv[cf][r] - m_[r]);
                rs_[r] += p;
                PL[w*1152 + ((l>>4)*4 + r)*72 + cf*16 + (l & 15)] = f2b(p);
            }
#pragma unroll
        for (int off = 1; off < 16; off <<= 1)
#pragma unroll
            for (int r = 0; r < 4; ++r)
                rs_[r] += __shfl_xor(rs_[r], off, 64);
#pragma unroll
        for (int r = 0; r < 4; ++r)
            ls_[r] = ls_[r] * fct[r] + rs_[r];
        // rescale O, then O += P*V
#pragma unroll
        for (int vf = 0; vf < 4; ++vf)
#pragma unroll
            for (int r = 0; r < 4; ++r)
                o[vf][r] *= fct[r];
        bf16x8 pa[2];
#pragma unroll
        for (int ks = 0; ks < 2; ++ks)
            pa[ks] = *(const bf16x8*)&PL[w*1152 + (l&15)*72 + ks*32 + (l>>4)*8];
#pragma unroll
        for (int vf = 0; vf < 4; ++vf)
#pragma unroll
            for (int ks = 0; ks < 2; ++ks) {
                const int row = vf*16 + (l & 15);
                const int ch = ((l>>4) + ks*4) ^ (row & 7);
                const bf16x8 vfr = *(const bf16x8*)&VT[row*64 + ch*8];
                o[vf] = MFMA(pa[ks], vfr, o[vf]);
            }
    }
    float inv[4];
#pragma unroll
    for (int r = 0; r < 4; ++r) inv[r] = 1.f / ls_[r];
#pragma unroll
    for (int vf = 0; vf < 4; ++vf)
#pragma unroll
        for (int r = 0; r < 4; ++r) {
            const long q = q0 + w*16 + (l>>4)*4 + r;
            pre2b[((long)b*Cn + q)*1024 + h*64 + vf*16 + (l&15)] = f2b(o[vf][r] * inv[r]);
        }
}

// ---------------------------------------------------------------------------
// Fused residual + LayerNorm; optional bf16 twin output.
// ---------------------------------------------------------------------------
template<bool WB16>
__global__ __launch_bounds__(256) void ln_res(
    const float* __restrict__ a, const float* __restrict__ r,
    const float* __restrict__ g, const float* __restrict__ be,
    float* __restrict__ out, u16* __restrict__ outb)
{
    __shared__ float wsum[4];
    __shared__ float wsum2[4];
    const long row = blockIdx.x;
    const int t = threadIdx.x;
    float4 va = *(const float4*)&a[row * Mn + t * 4];
    float4 vb = *(const float4*)&r[row * Mn + t * 4];
    float v0 = va.x + vb.x, v1 = va.y + vb.y, v2 = va.z + vb.z, v3 = va.w + vb.w;

    float s = v0 + v1 + v2 + v3;
#pragma unroll
    for (int off = 32; off > 0; off >>= 1) s += __shfl_xor(s, off, 64);
    if ((t & 63) == 0) wsum[t >> 6] = s;
    __syncthreads();
    float mu = (wsum[0] + wsum[1] + wsum[2] + wsum[3]) * (1.0f / Mn);

    float d0 = v0 - mu, d1 = v1 - mu, d2 = v2 - mu, d3 = v3 - mu;
    float s2 = d0 * d0 + d1 * d1 + d2 * d2 + d3 * d3;
#pragma unroll
    for (int off = 32; off > 0; off >>= 1) s2 += __shfl_xor(s2, off, 64);
    if ((t & 63) == 0) wsum2[t >> 6] = s2;
    __syncthreads();
    float var = (wsum2[0] + wsum2[1] + wsum2[2] + wsum2[3]) * (1.0f / Mn);
    float rstd = rsqrtf(var + EPSf);

    float4 g4 = *(const float4*)&g[t * 4];
    float4 b4 = *(const float4*)&be[t * 4];
    float4 r4;
    r4.x = d0 * rstd * g4.x + b4.x;
    r4.y = d1 * rstd * g4.y + b4.y;
    r4.z = d2 * rstd * g4.z + b4.z;
    r4.w = d3 * rstd * g4.w + b4.w;
    *(float4*)&out[row * Mn + t * 4] = r4;
    if (WB16) {
        ushort4 ob;
        ob.x = f2b(r4.x); ob.y = f2b(r4.y); ob.z = f2b(r4.z); ob.w = f2b(r4.w);
        *(ushort4*)&outb[row * Mn + t * 4] = ob;
    }
}

// ---------------------------------------------------------------------------
// Orchestration. Workspace byte offsets (MB), peak 84MB:
//  x_hi 0(8), x_lo 8(8), wqkTh 16(4), wqkTl 20(4), wvT 24(2), woT 26(2),
//  qk_hi 28(16), qk_lo 44(16), vb 60(8), vTb 68(8), pre2b 76(8)
//  reuse: attn_tmp 28(f32,16), h1 44(f32,16), h1b 60(8), w1T 68(8),
//         w2T 76(8), sbuf 0(32), ffn 60(f32,16 — over dead h1b/w1T;
//         MUST NOT overlap sbuf 0-32: that race caused round-6's NaN)
// ---------------------------------------------------------------------------
extern "C" void kernel_launch(void* const* d_in, const int* in_sizes, int n_in,
                              void* d_out, int out_size, void* d_ws, size_t ws_size,
                              hipStream_t stream)
{
    const float* x    = (const float*)d_in[0];
    const float* wq   = (const float*)d_in[1];
    const float* wk   = (const float*)d_in[2];
    const float* wv   = (const float*)d_in[3];
    const float* wo   = (const float*)d_in[4];
    const float* ln1g = (const float*)d_in[5];
    const float* ln1b = (const float*)d_in[6];
    const float* w1   = (const float*)d_in[7];
    const float* b1   = (const float*)d_in[8];
    const float* w2   = (const float*)d_in[9];
    const float* b2   = (const float*)d_in[10];
    const float* ln2g = (const float*)d_in[11];
    const float* ln2b = (const float*)d_in[12];
    float* out = (float*)d_out;

    char* W = (char*)d_ws;
    u16* x_hi  = (u16*)(W + 0*MB);
    u16* x_lo  = (u16*)(W + 8*MB);
    u16* wqkTh = (u16*)(W + 16*MB);
    u16* wqkTl = (u16*)(W + 20*MB);
    u16* wvT   = (u16*)(W + 24*MB);
    u16* woT   = (u16*)(W + 26*MB);
    u16* qk_hi = (u16*)(W + 28*MB);
    u16* qk_lo = (u16*)(W + 44*MB);
    u16* vb    = (u16*)(W + 60*MB);
    u16* vTb   = (u16*)(W + 68*MB);
    u16* pre2b = (u16*)(W + 76*MB);
    float* attn_tmp = (float*)(W + 28*MB);
    float* h1  = (float*)(W + 44*MB);
    u16* h1b   = (u16*)(W + 60*MB);
    u16* w1T   = (u16*)(W + 68*MB);
    u16* w2T   = (u16*)(W + 76*MB);
    u16* sbuf  = (u16*)(W + 0*MB);
    float* ffn = (float*)(W + 60*MB);   // over dead h1b/w1T; clear of sbuf

    // 1) conversions
    split_cvt<<<2048, 256, 0, stream>>>(x, x_hi, x_lo);
    tcvt<true ><<<dim3(1,16,16), 256, 0, stream>>>(wq, wqkTh, wqkTl, 1024, 64);
    tcvt<true ><<<dim3(1,16,16), 256, 0, stream>>>(wk, wqkTh + 1048576, wqkTl + 1048576, 1024, 64);
    tcvt<false><<<dim3(1,16,16), 256, 0, stream>>>(wv, wvT, nullptr, 1024, 64);
    tcvt<false><<<dim3(16,16,1), 256, 0, stream>>>(wo, woT, nullptr, 1024, 1024);

    // 2) fused q||k projection (split in, split out; q cols scaled 1/8)
    gemm128<true,true,true,false,false><<<dim3(16,32), 256, 0, stream>>>(
        x_hi, x_lo, wqkTh, wqkTl, nullptr, qk_hi, qk_lo,
        0.125f, 1.0f, 1024, 1024, 1024, 1024, 2048);
    // v projection (plain bf16)
    gemm128<false,false,true,false,false><<<dim3(8,32), 256, 0, stream>>>(
        x_hi, nullptr, wvT, nullptr, nullptr, vb, nullptr,
        1.f, 1.f, 0, 1024, 1024, 1024, 1024);
    ttrans2<<<dim3(32,1,32), 256, 0, stream>>>(vb, vTb);

    // 3) flash attention -> pre2b (B*C, H*V) bf16
    attn_mfma<<<dim3(32,32), 256, 0, stream>>>(qk_hi, qk_lo, vTb, pre2b);

    // 4) late weight transposes into freed regions
    tcvt<false><<<dim3(64,16,1), 256, 0, stream>>>(w1, w1T, nullptr, 1024, 4096);

    // 5) attn_out = pre2b @ woT^T -> f32
    gemm128<false,false,false,false,false><<<dim3(8,32), 256, 0, stream>>>(
        pre2b, nullptr, woT, nullptr, nullptr, attn_tmp, nullptr,
        1.f, 1.f, 0, 1024, 1024, 1024, 1024);
    tcvt<false><<<dim3(16,64,1), 256, 0, stream>>>(w2, w2T, nullptr, 4096, 1024);

    // 6) h1 = LN(x + attn_out) -> f32 + bf16
    ln_res<true ><<<Bn*Cn, 256, 0, stream>>>(x, attn_tmp, ln1g, ln1b, h1, h1b);

    // 7) s = relu(h1 @ w1 + b1) -> bf16
    gemm128<false,false,true,true,true ><<<dim3(32,32), 256, 0, stream>>>(
        h1b, nullptr, w1T, nullptr, b1, sbuf, nullptr,
        1.f, 1.f, 0, 1024, 1024, 1024, 4096);

    // 8) ffn = s @ w2 + b2 -> f32  (ffn @60 over dead h1b/w1T)
    gemm128<false,false,false,true,false><<<dim3(8,32), 256, 0, stream>>>(
        sbuf, nullptr, w2T, nullptr, b2, ffn, nullptr,
        1.f, 1.f, 0, 4096, 4096, 4096, 1024);

    // 9) out = LN(h1 + ffn)
    ln_res<false><<<Bn*Cn, 256, 0, stream>>>(h1, ffn, ln2g, ln2b, out, nullptr);
}